// Round 9
// baseline (116.102 us; speedup 1.0000x reference)
//
#include <hip/hip_runtime.h>
#include <hip/hip_bf16.h>
#include <hip/hip_fp16.h>
#include <cstdint>
#include <cstddef>

#define HH 64
#define WW 64
#define CIN 256
#define COUT 256
#define NB 8
#define HW (HH * WW)
#define BN_EPS 1e-5f

typedef __attribute__((ext_vector_type(8))) short s16x8;
typedef __attribute__((ext_vector_type(8))) unsigned short u16x8;
typedef __attribute__((ext_vector_type(4))) float f32x4;

static __device__ __forceinline__ float bf2f(unsigned short u) {
  unsigned int v = ((unsigned int)u) << 16;
  return __builtin_bit_cast(float, v);
}
static __device__ __forceinline__ unsigned short f2bf(float f) {
  __hip_bfloat16 h = __float2bfloat16(f);
  return __builtin_bit_cast(unsigned short, h);
}

// ---------------------------------------------------------------------------
// Kernel 1: x NCHW fp32 -> xbf NHWC bf16.  XCD swizzle: b = bid&7.
// ---------------------------------------------------------------------------
__global__ __launch_bounds__(256) void k_tr(const float* __restrict__ x,
                                            unsigned short* __restrict__ xbf) {
  __shared__ float tile[64][65];
  int bid = blockIdx.x;
  int b = bid & 7;
  int r = bid >> 3;
  int ct = r & 3;
  int st = r >> 2;
  int lane = threadIdx.x & 63;
  int grp = threadIdx.x >> 6;
  int c0 = ct * 64, s0 = st * 64;
  const float* xb = x + (size_t)b * CIN * HW;
#pragma unroll
  for (int i = 0; i < 16; ++i) {
    int row = grp * 16 + i;
    tile[row][lane] = xb[(size_t)(c0 + row) * HW + s0 + lane];
  }
  __syncthreads();
  unsigned short* xo = xbf + (size_t)b * HW * CIN;
#pragma unroll
  for (int i = 0; i < 16; ++i) {
    int row = grp * 16 + i;
    xo[(size_t)(s0 + row) * CIN + c0 + lane] = f2bf(tile[lane][row]);
  }
}

// ---------------------------------------------------------------------------
// Kernel 2: dc_w [o][c][3][3] fp32 -> Wf in MFMA FRAGMENT ORDER:
// Wf[k][ks][tile][lane][j]  (o = tile*16+(lane&15), c = ks*32+(lane>>4)*8+j)
// ---------------------------------------------------------------------------
__global__ __launch_bounds__(256) void k_wt(const float* __restrict__ dc_w,
                                            unsigned short* __restrict__ Wf) {
  int idx = blockIdx.x * 256 + threadIdx.x;
  if (idx >= 9 * 8 * 16 * 64 * 8) return;
  int j = idx & 7;
  int lane = (idx >> 3) & 63;
  int tile = (idx >> 9) & 15;
  int ks = (idx >> 13) & 7;
  int k = idx >> 16;
  int o = tile * 16 + (lane & 15);
  int c = ks * 32 + (lane >> 4) * 8 + j;
  Wf[idx] = f2bf(dc_w[((size_t)o * CIN + c) * 9 + k]);
}

// ---------------------------------------------------------------------------
// Kernel 3: off_w [ko][c][3][3] fp32 -> OWf fragment order:
// OWf[t][ks][kot][lane][j]  (ko = kot*16 + (lane&15), c = ks*32+(lane>>4)*8+j)
// ---------------------------------------------------------------------------
__global__ __launch_bounds__(256) void k_owt(const float* __restrict__ off_w,
                                             unsigned short* __restrict__ OWf) {
  int idx = blockIdx.x * 256 + threadIdx.x;
  if (idx >= 9 * 8 * 2 * 64 * 8) return;
  int j = idx & 7;
  int lane = (idx >> 3) & 63;
  int kot = (idx >> 9) & 1;
  int ks = (idx >> 10) & 7;
  int t = idx >> 13;
  int ko = kot * 16 + (lane & 15);
  int c = ks * 32 + (lane >> 4) * 8 + j;
  unsigned short v = 0;
  if (ko < 27) v = f2bf(off_w[((size_t)ko * CIN + c) * 9 + t]);
  OWf[idx] = v;
}

// ---------------------------------------------------------------------------
// Kernel 4: fold BN + conv bias
// ---------------------------------------------------------------------------
__global__ void k_bn(const float* __restrict__ g, const float* __restrict__ be,
                     const float* __restrict__ m, const float* __restrict__ va,
                     const float* __restrict__ db, float* __restrict__ sc,
                     float* __restrict__ bi) {
  int o = threadIdx.x;
  float s = g[o] * rsqrtf(va[o] + BN_EPS);
  sc[o] = s;
  bi[o] = be[o] + (db[o] - m[o]) * s;
}

// ---------------------------------------------------------------------------
// Kernel 5: FUSED offset-conv (MFMA) + deformable conv (MFMA) + BN + ReLU.
// 512 threads / 8 waves.  BISECT build:
//   Phase 1 = EXACT round-7 math, computed by waves 0-3 only (both kot halves
//             per wave, acc_oc[2]); barriers kept in uniform control flow.
//   Phase 2 = round-8 split (wave owns 32o x 64p, acc[2][4], stages 8 px).
// ---------------------------------------------------------------------------
__global__ __launch_bounds__(512, 2) void k_main(
    const unsigned short* __restrict__ xbf, const unsigned short* __restrict__ OWf,
    const float* __restrict__ off_b, const unsigned short* __restrict__ Wf,
    const float* __restrict__ bnsc, const float* __restrict__ bnbi,
    float* __restrict__ out) {
  int bid = blockIdx.x;
  int b = bid & 7;
  int h = bid >> 3;
  int tid = threadIdx.x;
  int lane = tid & 63;
  int wave = tid >> 6;
  int l15 = lane & 15, l4 = lane >> 4;

  __shared__ __align__(16) unsigned short ubuf[66 * 256];  // 33.8KB
  __shared__ float om_lds[27][64];                         // 6.9KB
  __shared__ unsigned short pre_offS[9][64][4];            // 4.6KB (pixel idx)
  __shared__ __half pre_wH[9][64][4];                      // 4.6KB

  const unsigned short* xb = xbf + (size_t)b * HW * CIN;

  // ================= Phase 1: offset conv via MFMA (round-7 math) ==========
  if (tid < 64) {
    int r = (tid < 32) ? 0 : 65;
    int ch = tid & 31;
    u16x8 z = {0, 0, 0, 0, 0, 0, 0, 0};
    *(u16x8*)&ubuf[r * 256 + ch * 8] = z;
  }

  f32x4 acc_oc[2];
  acc_oc[0] = (f32x4){0.f, 0.f, 0.f, 0.f};
  acc_oc[1] = (f32x4){0.f, 0.f, 0.f, 0.f};
  int wavepx = (wave & 3) * 16;

  for (int kh = 0; kh < 3; ++kh) {
    int y = h + kh - 1;
    if (y < 0 || y >= HH) continue;  // block-uniform
    __syncthreads();
    const unsigned short* src = xb + (size_t)y * WW * CIN;
#pragma unroll
    for (int i = 0; i < 4; ++i) {
      int e8 = i * 512 + tid;
      int px = e8 >> 5;
      int ch = e8 & 31;
      u16x8 v = *(const u16x8*)(src + e8 * 8);
      *(u16x8*)&ubuf[(px + 1) * 256 + ((ch ^ ((px + 1) & 7)) * 8)] = v;
    }
    __syncthreads();
    if (wave < 4) {  // round-7 compute: each wave does BOTH kot halves
#pragma unroll
      for (int kw = 0; kw < 3; ++kw) {
        int prow = wavepx + l15 + kw;
        int rs = prow & 7;
        const unsigned short* Atap =
            OWf + ((size_t)(kh * 3 + kw) * 8) * 1024 + lane * 8;
#pragma unroll
        for (int ks = 0; ks < 8; ++ks) {
          s16x8 bfrag = *(const s16x8*)&ubuf[prow * 256 + (((ks * 4 + l4) ^ rs) * 8)];
#pragma unroll
          for (int kot = 0; kot < 2; ++kot) {
            s16x8 afrag = *(const s16x8*)(Atap + ks * 1024 + kot * 512);
            acc_oc[kot] = __builtin_amdgcn_mfma_f32_16x16x32_bf16(afrag, bfrag,
                                                                  acc_oc[kot], 0, 0, 0);
          }
        }
      }
    }
  }
  if (wave < 4) {
#pragma unroll
    for (int kot = 0; kot < 2; ++kot) {
#pragma unroll
      for (int j = 0; j < 4; ++j) {
        int ko = kot * 16 + l4 * 4 + j;
        if (ko < 27) om_lds[ko][wavepx + l15] = acc_oc[kot][j];
      }
    }
  }
  __syncthreads();

  // ============ precompute per-(k,w) tap pixel-idx + weights ============
  for (int item = tid; item < 9 * 64; item += 512) {
    int k = item >> 6;
    int w = item & 63;
    int kh = k / 3, kw = k % 3;
    float offy = om_lds[2 * k][w] + off_b[2 * k];
    float offx = om_lds[2 * k + 1][w] + off_b[2 * k + 1];
    float mk = om_lds[18 + k][w] + off_b[18 + k];
    mk = 1.0f / (1.0f + expf(-mk));
    float py = (float)(h - 1 + kh) + offy;
    float px = (float)(w - 1 + kw) + offx;
    float fy0 = floorf(py), fx0 = floorf(px);
    float wy1 = py - fy0, wx1 = px - fx0;
    int y0 = (int)fy0, x0 = (int)fx0;
    int y1 = y0 + 1, x1 = x0 + 1;
    bool vy0 = (y0 >= 0) && (y0 <= HH - 1);
    bool vy1 = (y1 >= 0) && (y1 <= HH - 1);
    bool vx0 = (x0 >= 0) && (x0 <= WW - 1);
    bool vx1 = (x1 >= 0) && (x1 <= WW - 1);
    int y0c = min(max(y0, 0), HH - 1), y1c = min(max(y1, 0), HH - 1);
    int x0c = min(max(x0, 0), WW - 1), x1c = min(max(x1, 0), WW - 1);
    pre_wH[k][w][0] =
        __float2half((1.f - wy1) * (1.f - wx1) * mk * ((vy0 && vx0) ? 1.f : 0.f));
    pre_wH[k][w][1] = __float2half((1.f - wy1) * wx1 * mk * ((vy0 && vx1) ? 1.f : 0.f));
    pre_wH[k][w][2] = __float2half(wy1 * (1.f - wx1) * mk * ((vy1 && vx0) ? 1.f : 0.f));
    pre_wH[k][w][3] = __float2half(wy1 * wx1 * mk * ((vy1 && vx1) ? 1.f : 0.f));
    pre_offS[k][w][0] = (unsigned short)(y0c * WW + x0c);
    pre_offS[k][w][1] = (unsigned short)(y0c * WW + x1c);
    pre_offS[k][w][2] = (unsigned short)(y1c * WW + x0c);
    pre_offS[k][w][3] = (unsigned short)(y1c * WW + x1c);
  }

  // ================= Phase 2: deformable conv (round-8 split) =============
  unsigned short(*S)[256] = (unsigned short(*)[256])ubuf;
  f32x4 acc[2][4];
#pragma unroll
  for (int i = 0; i < 2; ++i)
#pragma unroll
    for (int j = 0; j < 4; ++j) acc[i][j] = (f32x4){0.f, 0.f, 0.f, 0.f};

  int pswz = lane & 7;
  int o_base = wave * 32;
  int hv = lane >> 5;     // pixel select within pass
  int chunk = lane & 31;  // 8-channel chunk

  for (int k = 0; k < 9; ++k) {
    __syncthreads();
    // ---- stage S: 8 px per wave (4 passes of 2), all 4 taps per lane ----
    {
#pragma unroll
      for (int pp = 0; pp < 4; ++pp) {
        int px = wave * 8 + pp * 2 + hv;
        int i0 = ((int)pre_offS[k][px][0]) << 8;
        int i1 = ((int)pre_offS[k][px][1]) << 8;
        int i2 = ((int)pre_offS[k][px][2]) << 8;
        int i3 = ((int)pre_offS[k][px][3]) << 8;
        float w0 = __half2float(pre_wH[k][px][0]);
        float w1 = __half2float(pre_wH[k][px][1]);
        float w2 = __half2float(pre_wH[k][px][2]);
        float w3 = __half2float(pre_wH[k][px][3]);
        u16x8 v0 = *(const u16x8*)(xb + i0 + chunk * 8);
        u16x8 v1 = *(const u16x8*)(xb + i1 + chunk * 8);
        u16x8 v2 = *(const u16x8*)(xb + i2 + chunk * 8);
        u16x8 v3 = *(const u16x8*)(xb + i3 + chunk * 8);
        u16x8 r;
#pragma unroll
        for (int j = 0; j < 8; ++j) {
          float s = w0 * bf2f(v0[j]) + w1 * bf2f(v1[j]) + w2 * bf2f(v2[j]) +
                    w3 * bf2f(v3[j]);
          r[j] = f2bf(s);
        }
        int phys = chunk ^ (px & 7);
        *(u16x8*)&S[px][phys * 8] = r;
      }
    }
    __syncthreads();
    // ---- MFMA over K=256 (8 K-steps of 32); A-frags coalesced from Wf ----
    const unsigned short* Wa = Wf + (size_t)k * 65536 + (wave * 2) * 512 + lane * 8;
#pragma unroll
    for (int ks = 0; ks < 8; ++ks) {
      s16x8 a[2], bf[4];
#pragma unroll
      for (int ot = 0; ot < 2; ++ot)
        a[ot] = *(const s16x8*)(Wa + ks * 8192 + ot * 512);
#pragma unroll
      for (int pt = 0; pt < 4; ++pt) {
        int slot = (ks * 4 + l4) ^ pswz;
        bf[pt] = *(const s16x8*)&S[pt * 16 + l15][slot * 8];
      }
#pragma unroll
      for (int ot = 0; ot < 2; ++ot)
#pragma unroll
        for (int pt = 0; pt < 4; ++pt)
          acc[ot][pt] = __builtin_amdgcn_mfma_f32_16x16x32_bf16(a[ot], bf[pt],
                                                                acc[ot][pt], 0, 0, 0);
    }
  }

  // ---- epilogue: BN + ReLU;  C/D: col=lane&15 (p), row=(lane>>4)*4+j (o) ----
#pragma unroll
  for (int ot = 0; ot < 2; ++ot) {
#pragma unroll
    for (int j = 0; j < 4; ++j) {
      int o = o_base + ot * 16 + l4 * 4 + j;
      float sc = bnsc[o], bi = bnbi[o];
      float* ob = out + (((size_t)b * COUT + o) * HH + h) * WW;
#pragma unroll
      for (int pt = 0; pt < 4; ++pt) {
        ob[pt * 16 + l15] = fmaxf(fmaf(acc[ot][pt][j], sc, bi), 0.f);
      }
    }
  }
}

// ---------------------------------------------------------------------------
extern "C" void kernel_launch(void* const* d_in, const int* in_sizes, int n_in,
                              void* d_out, int out_size, void* d_ws, size_t ws_size,
                              hipStream_t stream) {
  const float* x = (const float*)d_in[0];
  const float* off_w = (const float*)d_in[1];
  const float* off_b = (const float*)d_in[2];
  const float* dc_w = (const float*)d_in[3];
  const float* dc_b = (const float*)d_in[4];
  const float* bn_gamma = (const float*)d_in[5];
  const float* bn_beta = (const float*)d_in[6];
  const float* bn_mean = (const float*)d_in[7];
  const float* bn_var = (const float*)d_in[8];
  float* out = (float*)d_out;

  // workspace layout
  char* ws = (char*)d_ws;
  unsigned short* xbf = (unsigned short*)ws;  // 16.78 MB
  ws += (size_t)NB * HW * CIN * sizeof(unsigned short);
  unsigned short* Wf = (unsigned short*)ws;  // 1.18 MB
  ws += (size_t)9 * 8 * 16 * 64 * 8 * sizeof(unsigned short);
  unsigned short* OWf = (unsigned short*)ws;  // 147 KB
  ws += (size_t)9 * 8 * 2 * 64 * 8 * sizeof(unsigned short);
  float* bnsc = (float*)ws;
  ws += 256 * sizeof(float);
  float* bnbi = (float*)ws;

  k_tr<<<NB * 64 * 4, 256, 0, stream>>>(x, xbf);
  k_wt<<<(9 * 8 * 16 * 64 * 8 + 255) / 256, 256, 0, stream>>>(dc_w, Wf);
  k_owt<<<(9 * 8 * 2 * 64 * 8 + 255) / 256, 256, 0, stream>>>(off_w, OWf);
  k_bn<<<1, 256, 0, stream>>>(bn_gamma, bn_beta, bn_mean, bn_var, dc_b, bnsc, bnbi);
  k_main<<<NB * HH, 512, 0, stream>>>(xbf, OWf, off_b, Wf, bnsc, bnbi, out);
}

// Round 10
// 106.104 us; speedup vs baseline: 1.0942x; 1.0942x over previous
//
#include <hip/hip_runtime.h>
#include <hip/hip_bf16.h>
#include <hip/hip_fp16.h>
#include <cstdint>
#include <cstddef>

#define HH 64
#define WW 64
#define CIN 256
#define COUT 256
#define NB 8
#define HW (HH * WW)
#define BN_EPS 1e-5f

typedef __attribute__((ext_vector_type(8))) short s16x8;
typedef __attribute__((ext_vector_type(8))) unsigned short u16x8;
typedef __attribute__((ext_vector_type(4))) float f32x4;

static __device__ __forceinline__ float bf2f(unsigned short u) {
  unsigned int v = ((unsigned int)u) << 16;
  return __builtin_bit_cast(float, v);
}
static __device__ __forceinline__ unsigned short f2bf(float f) {
  __hip_bfloat16 h = __float2bfloat16(f);
  return __builtin_bit_cast(unsigned short, h);
}

// ---------------------------------------------------------------------------
// Kernel 1: x NCHW fp32 -> xbf NHWC bf16.  XCD swizzle: b = bid&7.
// ---------------------------------------------------------------------------
__global__ __launch_bounds__(256) void k_tr(const float* __restrict__ x,
                                            unsigned short* __restrict__ xbf) {
  __shared__ float tile[64][65];
  int bid = blockIdx.x;
  int b = bid & 7;
  int r = bid >> 3;
  int ct = r & 3;
  int st = r >> 2;
  int lane = threadIdx.x & 63;
  int grp = threadIdx.x >> 6;
  int c0 = ct * 64, s0 = st * 64;
  const float* xb = x + (size_t)b * CIN * HW;
#pragma unroll
  for (int i = 0; i < 16; ++i) {
    int row = grp * 16 + i;
    tile[row][lane] = xb[(size_t)(c0 + row) * HW + s0 + lane];
  }
  __syncthreads();
  unsigned short* xo = xbf + (size_t)b * HW * CIN;
#pragma unroll
  for (int i = 0; i < 16; ++i) {
    int row = grp * 16 + i;
    xo[(size_t)(s0 + row) * CIN + c0 + lane] = f2bf(tile[lane][row]);
  }
}

// ---------------------------------------------------------------------------
// Kernel 2: dc_w [o][c][3][3] fp32 -> Wf in MFMA FRAGMENT ORDER:
// Wf[k][ks][tile][lane][j]  (o = tile*16+(lane&15), c = ks*32+(lane>>4)*8+j)
// ---------------------------------------------------------------------------
__global__ __launch_bounds__(256) void k_wt(const float* __restrict__ dc_w,
                                            unsigned short* __restrict__ Wf) {
  int idx = blockIdx.x * 256 + threadIdx.x;
  if (idx >= 9 * 8 * 16 * 64 * 8) return;
  int j = idx & 7;
  int lane = (idx >> 3) & 63;
  int tile = (idx >> 9) & 15;
  int ks = (idx >> 13) & 7;
  int k = idx >> 16;
  int o = tile * 16 + (lane & 15);
  int c = ks * 32 + (lane >> 4) * 8 + j;
  Wf[idx] = f2bf(dc_w[((size_t)o * CIN + c) * 9 + k]);
}

// ---------------------------------------------------------------------------
// Kernel 3: off_w [ko][c][3][3] fp32 -> OWf fragment order:
// OWf[t][ks][kot][lane][j]  (ko = kot*16 + (lane&15), c = ks*32+(lane>>4)*8+j)
// ---------------------------------------------------------------------------
__global__ __launch_bounds__(256) void k_owt(const float* __restrict__ off_w,
                                             unsigned short* __restrict__ OWf) {
  int idx = blockIdx.x * 256 + threadIdx.x;
  if (idx >= 9 * 8 * 2 * 64 * 8) return;
  int j = idx & 7;
  int lane = (idx >> 3) & 63;
  int kot = (idx >> 9) & 1;
  int ks = (idx >> 10) & 7;
  int t = idx >> 13;
  int ko = kot * 16 + (lane & 15);
  int c = ks * 32 + (lane >> 4) * 8 + j;
  unsigned short v = 0;
  if (ko < 27) v = f2bf(off_w[((size_t)ko * CIN + c) * 9 + t]);
  OWf[idx] = v;
}

// ---------------------------------------------------------------------------
// Kernel 4: fold BN + conv bias
// ---------------------------------------------------------------------------
__global__ void k_bn(const float* __restrict__ g, const float* __restrict__ be,
                     const float* __restrict__ m, const float* __restrict__ va,
                     const float* __restrict__ db, float* __restrict__ sc,
                     float* __restrict__ bi) {
  int o = threadIdx.x;
  float s = g[o] * rsqrtf(va[o] + BN_EPS);
  sc[o] = s;
  bi[o] = be[o] + (db[o] - m[o]) * s;
}

// ---------------------------------------------------------------------------
// Kernel 5: FUSED offset-conv (MFMA) + deformable conv (MFMA) + BN + ReLU.
// PIXEL-SPLIT: block = (b, h, q); 256 threads / 4 waves; 32 px x 256 o.
// Grid 1024 = 4 blocks/CU (LDS 25KB) -> cross-block stage/MFMA overlap.
// Phase 1: r9-verified pattern (waves 0-1 compute, both kot halves each).
// Phase 2: r7 structure, wave owns 64o x 32px (acc[4][2]).
// ---------------------------------------------------------------------------
__global__ __launch_bounds__(256, 4) void k_main(
    const unsigned short* __restrict__ xbf, const unsigned short* __restrict__ OWf,
    const float* __restrict__ off_b, const unsigned short* __restrict__ Wf,
    const float* __restrict__ bnsc, const float* __restrict__ bnbi,
    float* __restrict__ out) {
  int bid = blockIdx.x;
  int b = bid & 7;
  int r = bid >> 3;
  int h = r & 63;
  int q = r >> 6;        // pixel half (0..1)
  int wq = q * 32;       // global pixel base
  int tid = threadIdx.x;
  int lane = tid & 63;
  int wave = tid >> 6;
  int l15 = lane & 15, l4 = lane >> 4;

  __shared__ __align__(16) unsigned short ubuf[34 * 256];  // 17.4KB (rowbuf / S)
  __shared__ float om_lds[27][32];                         // 3.5KB
  __shared__ unsigned short pre_offS[9][32][4];            // 2.3KB (global px idx)
  __shared__ __half pre_wH[9][32][4];                      // 2.3KB

  const unsigned short* xb = xbf + (size_t)b * HW * CIN;

  // ================= Phase 1: offset conv via MFMA =================
  // rowbuf: padded cols 0..33 = global px (wq-1 .. wq+32); OOB -> zero.
  f32x4 acc_oc[2];
  acc_oc[0] = (f32x4){0.f, 0.f, 0.f, 0.f};
  acc_oc[1] = (f32x4){0.f, 0.f, 0.f, 0.f};
  int ptile = wave & 1;          // 16-px tile for phase-1 compute (waves 0-1)
  int gstart = wq - 1;

  for (int kh = 0; kh < 3; ++kh) {
    int y = h + kh - 1;
    if (y < 0 || y >= HH) continue;  // block-uniform
    __syncthreads();                 // prior readers done
    const unsigned short* srow = xb + (size_t)y * WW * CIN;
    for (int e = tid; e < 34 * 32; e += 256) {
      int col = e >> 5;   // padded col 0..33
      int ch = e & 31;
      int g = gstart + col;
      u16x8 v = {0, 0, 0, 0, 0, 0, 0, 0};
      if (g >= 0 && g < WW) v = *(const u16x8*)(srow + (size_t)g * CIN + ch * 8);
      *(u16x8*)&ubuf[col * 256 + ((ch ^ (col & 7)) * 8)] = v;
    }
    __syncthreads();
    if (wave < 2) {  // r9-verified: each wave does BOTH kot halves
#pragma unroll
      for (int kw = 0; kw < 3; ++kw) {
        int prow = ptile * 16 + l15 + kw;  // padded col index
        int rs = prow & 7;
        const unsigned short* Atap =
            OWf + ((size_t)(kh * 3 + kw) * 8) * 1024 + lane * 8;
#pragma unroll
        for (int ks = 0; ks < 8; ++ks) {
          s16x8 bfrag = *(const s16x8*)&ubuf[prow * 256 + (((ks * 4 + l4) ^ rs) * 8)];
#pragma unroll
          for (int kot = 0; kot < 2; ++kot) {
            s16x8 afrag = *(const s16x8*)(Atap + ks * 1024 + kot * 512);
            acc_oc[kot] = __builtin_amdgcn_mfma_f32_16x16x32_bf16(afrag, bfrag,
                                                                  acc_oc[kot], 0, 0, 0);
          }
        }
      }
    }
  }
  if (wave < 2) {
#pragma unroll
    for (int kot = 0; kot < 2; ++kot) {
#pragma unroll
      for (int j = 0; j < 4; ++j) {
        int ko = kot * 16 + l4 * 4 + j;
        if (ko < 27) om_lds[ko][ptile * 16 + l15] = acc_oc[kot][j];
      }
    }
  }
  __syncthreads();

  // ============ precompute per-(k, local w) tap pixel-idx + weights ============
  for (int item = tid; item < 9 * 32; item += 256) {
    int k = item >> 5;
    int wl = item & 31;       // local pixel
    int w = wq + wl;          // global pixel
    int kh = k / 3, kw = k % 3;
    float offy = om_lds[2 * k][wl] + off_b[2 * k];
    float offx = om_lds[2 * k + 1][wl] + off_b[2 * k + 1];
    float mk = om_lds[18 + k][wl] + off_b[18 + k];
    mk = 1.0f / (1.0f + expf(-mk));
    float py = (float)(h - 1 + kh) + offy;
    float px = (float)(w - 1 + kw) + offx;
    float fy0 = floorf(py), fx0 = floorf(px);
    float wy1 = py - fy0, wx1 = px - fx0;
    int y0 = (int)fy0, x0 = (int)fx0;
    int y1 = y0 + 1, x1 = x0 + 1;
    bool vy0 = (y0 >= 0) && (y0 <= HH - 1);
    bool vy1 = (y1 >= 0) && (y1 <= HH - 1);
    bool vx0 = (x0 >= 0) && (x0 <= WW - 1);
    bool vx1 = (x1 >= 0) && (x1 <= WW - 1);
    int y0c = min(max(y0, 0), HH - 1), y1c = min(max(y1, 0), HH - 1);
    int x0c = min(max(x0, 0), WW - 1), x1c = min(max(x1, 0), WW - 1);
    pre_wH[k][wl][0] =
        __float2half((1.f - wy1) * (1.f - wx1) * mk * ((vy0 && vx0) ? 1.f : 0.f));
    pre_wH[k][wl][1] = __float2half((1.f - wy1) * wx1 * mk * ((vy0 && vx1) ? 1.f : 0.f));
    pre_wH[k][wl][2] = __float2half(wy1 * (1.f - wx1) * mk * ((vy1 && vx0) ? 1.f : 0.f));
    pre_wH[k][wl][3] = __float2half(wy1 * wx1 * mk * ((vy1 && vx1) ? 1.f : 0.f));
    pre_offS[k][wl][0] = (unsigned short)(y0c * WW + x0c);
    pre_offS[k][wl][1] = (unsigned short)(y0c * WW + x1c);
    pre_offS[k][wl][2] = (unsigned short)(y1c * WW + x0c);
    pre_offS[k][wl][3] = (unsigned short)(y1c * WW + x1c);
  }

  // ================= Phase 2: deformable conv =================
  unsigned short(*S)[256] = (unsigned short(*)[256])ubuf;  // S[32][256]
  f32x4 acc[4][2];
#pragma unroll
  for (int i = 0; i < 4; ++i)
#pragma unroll
    for (int j = 0; j < 2; ++j) acc[i][j] = (f32x4){0.f, 0.f, 0.f, 0.f};

  int o_base = wave * 64;
  int hv = lane >> 5;     // pixel select within pass
  int chunk = lane & 31;  // 8-channel chunk

  for (int k = 0; k < 9; ++k) {
    __syncthreads();
    // ---- stage S: 8 px per wave (4 passes of 2), all 4 taps per lane ----
    {
#pragma unroll
      for (int pp = 0; pp < 4; ++pp) {
        int pl = wave * 8 + pp * 2 + hv;  // local pixel 0..31
        int i0 = ((int)pre_offS[k][pl][0]) << 8;
        int i1 = ((int)pre_offS[k][pl][1]) << 8;
        int i2 = ((int)pre_offS[k][pl][2]) << 8;
        int i3 = ((int)pre_offS[k][pl][3]) << 8;
        float w0 = __half2float(pre_wH[k][pl][0]);
        float w1 = __half2float(pre_wH[k][pl][1]);
        float w2 = __half2float(pre_wH[k][pl][2]);
        float w3 = __half2float(pre_wH[k][pl][3]);
        u16x8 v0 = *(const u16x8*)(xb + i0 + chunk * 8);
        u16x8 v1 = *(const u16x8*)(xb + i1 + chunk * 8);
        u16x8 v2 = *(const u16x8*)(xb + i2 + chunk * 8);
        u16x8 v3 = *(const u16x8*)(xb + i3 + chunk * 8);
        u16x8 rr;
#pragma unroll
        for (int j = 0; j < 8; ++j) {
          float s = w0 * bf2f(v0[j]) + w1 * bf2f(v1[j]) + w2 * bf2f(v2[j]) +
                    w3 * bf2f(v3[j]);
          rr[j] = f2bf(s);
        }
        int phys = chunk ^ (pl & 7);
        *(u16x8*)&S[pl][phys * 8] = rr;
      }
    }
    __syncthreads();
    // ---- MFMA over K=256 (8 K-steps of 32); A-frags coalesced from Wf ----
    const unsigned short* Wa = Wf + (size_t)k * 65536 + (wave * 4) * 512 + lane * 8;
#pragma unroll
    for (int ks = 0; ks < 8; ++ks) {
      s16x8 a[4], bf[2];
#pragma unroll
      for (int ot = 0; ot < 4; ++ot)
        a[ot] = *(const s16x8*)(Wa + ks * 8192 + ot * 512);
#pragma unroll
      for (int pt = 0; pt < 2; ++pt) {
        int pl = pt * 16 + l15;
        int slot = (ks * 4 + l4) ^ (pl & 7);
        bf[pt] = *(const s16x8*)&S[pl][slot * 8];
      }
#pragma unroll
      for (int ot = 0; ot < 4; ++ot)
#pragma unroll
        for (int pt = 0; pt < 2; ++pt)
          acc[ot][pt] = __builtin_amdgcn_mfma_f32_16x16x32_bf16(a[ot], bf[pt],
                                                                acc[ot][pt], 0, 0, 0);
    }
  }

  // ---- epilogue: BN + ReLU;  C/D: col=lane&15 (px), row=(lane>>4)*4+j (o) ----
#pragma unroll
  for (int ot = 0; ot < 4; ++ot) {
#pragma unroll
    for (int j = 0; j < 4; ++j) {
      int o = o_base + ot * 16 + l4 * 4 + j;
      float sc = bnsc[o], bi = bnbi[o];
      float* ob = out + (((size_t)b * COUT + o) * HH + h) * WW + wq;
#pragma unroll
      for (int pt = 0; pt < 2; ++pt) {
        ob[pt * 16 + l15] = fmaxf(fmaf(acc[ot][pt][j], sc, bi), 0.f);
      }
    }
  }
}

// ---------------------------------------------------------------------------
extern "C" void kernel_launch(void* const* d_in, const int* in_sizes, int n_in,
                              void* d_out, int out_size, void* d_ws, size_t ws_size,
                              hipStream_t stream) {
  const float* x = (const float*)d_in[0];
  const float* off_w = (const float*)d_in[1];
  const float* off_b = (const float*)d_in[2];
  const float* dc_w = (const float*)d_in[3];
  const float* dc_b = (const float*)d_in[4];
  const float* bn_gamma = (const float*)d_in[5];
  const float* bn_beta = (const float*)d_in[6];
  const float* bn_mean = (const float*)d_in[7];
  const float* bn_var = (const float*)d_in[8];
  float* out = (float*)d_out;

  // workspace layout
  char* ws = (char*)d_ws;
  unsigned short* xbf = (unsigned short*)ws;  // 16.78 MB
  ws += (size_t)NB * HW * CIN * sizeof(unsigned short);
  unsigned short* Wf = (unsigned short*)ws;  // 1.18 MB
  ws += (size_t)9 * 8 * 16 * 64 * 8 * sizeof(unsigned short);
  unsigned short* OWf = (unsigned short*)ws;  // 147 KB
  ws += (size_t)9 * 8 * 2 * 64 * 8 * sizeof(unsigned short);
  float* bnsc = (float*)ws;
  ws += 256 * sizeof(float);
  float* bnbi = (float*)ws;

  k_tr<<<NB * 64 * 4, 256, 0, stream>>>(x, xbf);
  k_wt<<<(9 * 8 * 16 * 64 * 8 + 255) / 256, 256, 0, stream>>>(dc_w, Wf);
  k_owt<<<(9 * 8 * 2 * 64 * 8 + 255) / 256, 256, 0, stream>>>(off_w, OWf);
  k_bn<<<1, 256, 0, stream>>>(bn_gamma, bn_beta, bn_mean, bn_var, dc_b, bnsc, bnbi);
  k_main<<<NB * HH * 2, 256, 0, stream>>>(xbf, OWf, off_b, Wf, bnsc, bnbi, out);
}